// Round 8
// baseline (213.837 us; speedup 1.0000x reference)
//
#include <hip/hip_runtime.h>

typedef unsigned short u16;
typedef __attribute__((ext_vector_type(4))) unsigned short u16x4;
typedef __attribute__((ext_vector_type(8))) unsigned short u16x8;
typedef __attribute__((ext_vector_type(4))) float          f32x4;
typedef __attribute__((ext_vector_type(8))) __bf16         bf16x8;

#define MFMA16(a,b,c) __builtin_amdgcn_mfma_f32_16x16x32_bf16((a),(b),(c),0,0,0)
#define SCALE 0.125f
// SCALE * log2(e): exp(s*SCALE) == exp2(s * SCALE_LOG2E). Folded into q/qt weights.
#define SCALE_LOG2E 0.18033688011112042f

__device__ __forceinline__ u16 f2b(float f){
  unsigned u = __builtin_bit_cast(unsigned, f);
  u = (u + 0x7fffu + ((u >> 16) & 1u)) >> 16;
  return (u16)u;
}
__device__ __forceinline__ u16 f2b_trunc(float f){
  return (u16)(__builtin_bit_cast(unsigned, f) >> 16);
}
__device__ __forceinline__ float b2f(u16 v){
  unsigned u = ((unsigned)v) << 16;
  return __builtin_bit_cast(float, u);
}
__device__ __forceinline__ void async16(const u16* g, u16* l){
  __builtin_amdgcn_global_load_lds(
      (const __attribute__((address_space(1))) unsigned*)g,
      (__attribute__((address_space(3))) unsigned*)l, 16, 0, 0);
}
// XOR-swizzled LDS addressing: rows of 64 u16 = 8 chunks of 8.
__device__ __forceinline__ int swz(int row, int chunk, int off){
  return row*64 + (((chunk ^ row ^ (row >> 3)) & 7) << 3) + off;
}

// ---------------- fused cast f32 -> bf16 over all 8 inputs ----------------
// q rows (0..511) and qt rows (1536..2047) of Wqkv are pre-scaled by
// SCALE*log2e so attention scores land directly in the exp2 domain.
// Block 0 also zeroes the 3 output-loss slots (stream order makes this safe:
// every atomicAdd into outs happens in a later launch).
__global__ void cast_all_k(const float* __restrict__ x, const float* __restrict__ y,
                           const float* __restrict__ wq1, const float* __restrict__ wq2,
                           const float* __restrict__ w1, const float* __restrict__ w2,
                           const float* __restrict__ w3, const float* __restrict__ w4,
                           u16* __restrict__ dst, float* __restrict__ outs){
  if (blockIdx.x == 0 && threadIdx.x < 3) outs[threadIdx.x] = 0.f;
  int i = blockIdx.x * 256 + threadIdx.x;            // float4 index, 1,835,008 total
  const float* s; int base; float sc = 1.f;
  if      (i < 524288)  { s = x;   base = 0;       }
  else if (i < 1048576) { s = y;   base = 524288;  }
  else if (i < 1310720) { s = wq1; base = 1048576;
    int iw = i - base; if (iw < 65536 || iw >= 196608) sc = SCALE_LOG2E; }
  else if (i < 1572864) { s = wq2; base = 1310720;
    int iw = i - base; if (iw < 65536 || iw >= 196608) sc = SCALE_LOG2E; }
  else if (i < 1638400) { s = w1;  base = 1572864; }
  else if (i < 1703936) { s = w2;  base = 1638400; }
  else if (i < 1769472) { s = w3;  base = 1703936; }
  else                  { s = w4;  base = 1769472; }
  float4 v = ((const float4*)s)[i - base];
  u16x4 o; o[0]=f2b(v.x*sc); o[1]=f2b(v.y*sc); o[2]=f2b(v.z*sc); o[3]=f2b(v.w*sc);
  ((u16x4*)dst)[i] = o;
}

// ---------------- mega QKV GEMM: all q/k/qt/vT tiles in one launch ----------------
// All sub-GEMMs share K=512 and row-stride-512 A,B. bf16 out. (round-3 proven form)
__global__ __launch_bounds__(256, 2) void qkv_mega_k(
    const u16* __restrict__ xb, const u16* __restrict__ Wq,
    u16* __restrict__ qkv, u16* __restrict__ vT)
{
  const int i = blockIdx.x;
  const u16 *A, *B; u16* C; int ldc, m0, n0;
  if (i < 512) {                 // q,k: M=4096,N=1024
    int z = i >> 8, t = i & 255;
    m0 = (t & 31)*128; n0 = (t >> 5)*128;
    A = xb + (size_t)z*2097152; B = Wq + (size_t)z*1048576;
    C = qkv + (size_t)z*8388608; ldc = 2048;
  } else if (i < 768) {          // qt: M=4096,N=512 -> cols 1536..2047
    int z = (i-512) >> 7, t = (i-512) & 127;
    m0 = (t & 31)*128; n0 = (t >> 5)*128;
    A = xb + (size_t)z*2097152; B = Wq + (size_t)z*1048576 + (size_t)1536*512;
    C = qkv + (size_t)z*8388608 + 1536; ldc = 2048;
  } else {                       // vT = Wv @ x^T: M=512,N=4096
    int z = (i-768) >> 7, t = (i-768) & 127;
    m0 = (t & 3)*128; n0 = (t >> 2)*128;
    A = Wq + (size_t)z*1048576 + (size_t)1024*512; B = xb + (size_t)z*2097152;
    C = vT + (size_t)z*2097152; ldc = 4096;
  }

  __shared__ u16 As[128*32];
  __shared__ u16 Bs[128*32];
  const int tid  = threadIdx.x;
  const int w    = tid >> 6, lane = tid & 63;
  const int quad = lane >> 4, l16 = lane & 15;
  const int wr   = w >> 1, wc = w & 1;

  f32x4 acc[4][4] = {};
  const int rowa = lane >> 2;
  const int ko   = (lane & 3) * 8;

  for (int k0 = 0; k0 < 512; k0 += 32) {
    __syncthreads();
#pragma unroll
    for (int r = 0; r < 2; ++r) {
      int rb = (r*4 + w) * 16;
      async16(A + (size_t)(m0 + rb + rowa)*512 + k0 + ko, As + (r*4 + w)*512);
      async16(B + (size_t)(n0 + rb + rowa)*512 + k0 + ko, Bs + (r*4 + w)*512);
    }
    __syncthreads();
    bf16x8 af[4], bfr[4];
#pragma unroll
    for (int ii = 0; ii < 4; ++ii)
      af[ii] = *(const bf16x8*)&As[(wr*64 + ii*16 + l16)*32 + quad*8];
#pragma unroll
    for (int j = 0; j < 4; ++j)
      bfr[j] = *(const bf16x8*)&Bs[(wc*64 + j*16 + l16)*32 + quad*8];
#pragma unroll
    for (int ii = 0; ii < 4; ++ii)
#pragma unroll
      for (int j = 0; j < 4; ++j)
        acc[ii][j] = MFMA16(af[ii], bfr[j], acc[ii][j]);
  }
#pragma unroll
  for (int j = 0; j < 4; ++j) {
    int col = n0 + wc*64 + j*16 + l16;
#pragma unroll
    for (int ii = 0; ii < 4; ++ii)
#pragma unroll
      for (int reg = 0; reg < 4; ++reg) {
        int row = m0 + wr*64 + ii*16 + quad*4 + reg;
        C[(size_t)row*ldc + col] = f2b(acc[ii][j][reg]);
      }
  }
}

// ------- final-linear GEMM (blocks 0..511) + orthoB reduction (512..575) ----
// GEMM: C[M,N] = A @ B^T + bias, f32 out, z = bid>>7. (round-3 proven body)
// orthoB blocks are independent of the GEMM (read Gbuf from attn_ortho) and
// run in the GEMM's occupancy shadow; they atomicAdd pre-scaled loss to outs.
__global__ __launch_bounds__(256, 2) void gemm_fin_k(
    const u16* __restrict__ A0, size_t aStr, const u16* __restrict__ B0, size_t bStr,
    const float* __restrict__ bias0, const float* __restrict__ bias1,
    const float* __restrict__ bias2, const float* __restrict__ bias3,
    float* __restrict__ C0, size_t cStr,
    const float* __restrict__ Gbuf, float* __restrict__ outs)
{
  const int tid  = threadIdx.x;
  const int bid  = blockIdx.x;
  if (bid >= 512) {
    // ---- orthoB: sum 8 tg-partials, Hadamard, reduce, pre-scaled add ----
    const int i = bid - 512;
    const int bh = i & 31, which = i >> 5;
    const float* base = Gbuf + (size_t)((which*32 + bh)*8) * 8192;
    float acc = 0.f;
    for (int idx = tid*4; idx < 4096; idx += 1024) {
      float4 gq = {0.f,0.f,0.f,0.f}, gt = {0.f,0.f,0.f,0.f};
#pragma unroll
      for (int t = 0; t < 8; ++t) {
        float4 a = *(const float4*)(base + (size_t)t*8192 + idx);
        float4 c = *(const float4*)(base + (size_t)t*8192 + 4096 + idx);
        gq.x += a.x; gq.y += a.y; gq.z += a.z; gq.w += a.w;
        gt.x += c.x; gt.y += c.y; gt.z += c.z; gt.w += c.w;
      }
      acc += gq.x*gt.x + gq.y*gt.y + gq.z*gt.z + gq.w*gt.w;
    }
    __shared__ float redsh[256];
    redsh[tid] = acc; __syncthreads();
    for (int s2 = 128; s2 > 0; s2 >>= 1) {
      if (tid < s2) redsh[tid] += redsh[tid + s2];
      __syncthreads();
    }
    if (tid == 0) atomicAdd(&outs[which], redsh[0] * (1.f/4194304.f));
    return;
  }

  const int z = bid >> 7, t7 = bid & 127;
  const int m0 = (t7 >> 2) * 128, n0 = (t7 & 3) * 128;
  const u16* A = A0 + (size_t)z * aStr;
  const u16* Bm = B0 + (size_t)z * bStr;
  float* Cb = C0 + (size_t)z * cStr;
  const float* bias = (z==0) ? bias0 : (z==1) ? bias1 : (z==2) ? bias2 : bias3;

  __shared__ u16 As[128*32];
  __shared__ u16 Bs[128*32];
  const int w    = tid >> 6, lane = tid & 63;
  const int quad = lane >> 4, l16 = lane & 15;
  const int wr   = w >> 1, wc = w & 1;

  f32x4 acc[4][4] = {};
  const int rowa = lane >> 2;
  const int ko   = (lane & 3) * 8;

  for (int k0 = 0; k0 < 512; k0 += 32) {
    __syncthreads();
#pragma unroll
    for (int r = 0; r < 2; ++r) {
      int rb = (r*4 + w) * 16;
      async16(A  + (size_t)(m0 + rb + rowa)*512 + k0 + ko, As + (r*4 + w)*512);
      async16(Bm + (size_t)(n0 + rb + rowa)*512 + k0 + ko, Bs + (r*4 + w)*512);
    }
    __syncthreads();
    bf16x8 af[4], bfr[4];
#pragma unroll
    for (int ii = 0; ii < 4; ++ii)
      af[ii] = *(const bf16x8*)&As[(wr*64 + ii*16 + l16)*32 + quad*8];
#pragma unroll
    for (int j = 0; j < 4; ++j)
      bfr[j] = *(const bf16x8*)&Bs[(wc*64 + j*16 + l16)*32 + quad*8];
#pragma unroll
    for (int ii = 0; ii < 4; ++ii)
#pragma unroll
      for (int j = 0; j < 4; ++j)
        acc[ii][j] = MFMA16(af[ii], bfr[j], acc[ii][j]);
  }
#pragma unroll
  for (int j = 0; j < 4; ++j) {
    int col = n0 + wc*64 + j*16 + l16;
    float bv = bias[col];
#pragma unroll
    for (int ii = 0; ii < 4; ++ii)
#pragma unroll
      for (int reg = 0; reg < 4; ++reg) {
        int row = m0 + wr*64 + ii*16 + quad*4 + reg;
        Cb[(size_t)row*512 + col] = acc[ii][j][reg] + bv;
      }
  }
}

// ---------------- merged attention + ortho: independent work, one launch --------
// Blocks 0..511: flash attention (round-5 proven body, XCD swizzle preserved).
// Blocks 512..1023: ortho Gram partials (round-6 proven body, diag pre-scaled).
__global__ __launch_bounds__(256, 2) void attn_ortho_k(
    const u16* __restrict__ qkv1, const u16* __restrict__ qkv2,
    const u16* __restrict__ vT1, const u16* __restrict__ vT2,
    u16* __restrict__ ao, float* __restrict__ Gbuf, float* __restrict__ outs)
{
  __shared__ u16 lds[24576];     // 48 KB union
  const int tid = threadIdx.x, w = tid >> 6, lane = tid & 63;
  const int quad = lane >> 4, l16 = lane & 15;

  if (blockIdx.x < 512) {
    // ================= attention path =================
    u16* Ks = lds;               // [2][4096]
    u16* Vt = lds + 8192;        // [2][4096]
    u16* Ps = lds + 16384;       // [4][2][1024]

    const int lin = blockIdx.x;
    const int xcd = lin & 7, slot = lin >> 3;        // slot 0..63
    const int g   = xcd + 8*(slot >> 3);             // group 0..63, g%8 == xcd
    const int qt  = slot & 7;                        // 8 q-tiles of 128 rows
    const int bh  = g >> 1, p = g & 1;
    const int b = bh >> 3, h = bh & 7;
    const u16* kvsrc = p ? qkv2 : qkv1;
    const u16* vsrc  = p ? vT2 : vT1;
    const u16* qsrcA = p ? qkv1 : qkv2;  const int qoffA = h*64;           // out a=p
    const u16* qsrcB = p ? qkv2 : qkv1;  const int qoffB = 1536 + h*64;    // out a=p+2
    const int koff = 512 + h*64;
    const size_t tb = (size_t)b * 1024;

    const int srow = tid >> 3, sch = tid & 7;

    u16x8 onesu;
#pragma unroll
    for (int ii = 0; ii < 8; ++ii) onesu[ii] = 0x3f80;
    const bf16x8 ONES = __builtin_bit_cast(bf16x8, onesu);

    bf16x8 qb[2][2][2];
#pragma unroll
    for (int s2 = 0; s2 < 2; ++s2) {
      size_t row = tb + qt*128 + w*32 + s2*16 + l16;
      const u16* qrA = qsrcA + row*2048 + qoffA;
      const u16* qrB = qsrcB + row*2048 + qoffB;
      qb[0][s2][0] = *(const bf16x8*)(qrA + quad*8);
      qb[0][s2][1] = *(const bf16x8*)(qrA + 32 + quad*8);
      qb[1][s2][0] = *(const bf16x8*)(qrB + quad*8);
      qb[1][s2][1] = *(const bf16x8*)(qrB + 32 + quad*8);
    }

    f32x4 oacc[2][2][4] = {};
    f32x4 lacc[2][2] = {};

    u16x8 kreg[2], vreg[2];
    auto loadTile = [&](int t){
#pragma unroll
      for (int r = 0; r < 2; ++r) {
        kreg[r] = *(const u16x8*)(kvsrc + (tb + t*64 + r*32 + srow)*2048 + koff + sch*8);
        vreg[r] = *(const u16x8*)(vsrc + (size_t)(h*64 + r*32 + srow)*4096 + tb + t*64 + sch*8);
      }
    };
    auto storeTile = [&](int buf){
#pragma unroll
      for (int r = 0; r < 2; ++r) {
        *(u16x8*)&Ks[buf*4096 + swz(r*32 + srow, sch, 0)] = kreg[r];
        *(u16x8*)&Vt[buf*4096 + swz(r*32 + srow, sch, 0)] = vreg[r];
      }
    };

    loadTile(0);
    storeTile(0);
    loadTile(1);

    for (int kt = 0; kt < 16; ++kt) {
      const int cur = kt & 1;
      __syncthreads();
      if (kt < 15) storeTile(cur ^ 1);
      if (kt < 14) loadTile(kt + 2);

      bf16x8 ka[4][2], vb[4][2];
#pragma unroll
      for (int j = 0; j < 4; ++j) {
        ka[j][0] = *(const bf16x8*)&Ks[cur*4096 + swz(j*16 + l16, quad, 0)];
        ka[j][1] = *(const bf16x8*)&Ks[cur*4096 + swz(j*16 + l16, quad + 4, 0)];
        vb[j][0] = *(const bf16x8*)&Vt[cur*4096 + swz(j*16 + l16, quad, 0)];
        vb[j][1] = *(const bf16x8*)&Vt[cur*4096 + swz(j*16 + l16, quad + 4, 0)];
      }

      bf16x8 paP0, paP1;
#pragma unroll
      for (int idx = 0; idx < 4; ++idx) {
        const int o = idx >> 1, s2 = idx & 1;
        u16* wP = Ps + w*2048 + (idx & 1)*1024;
        f32x4 t[4];
        __builtin_amdgcn_s_setprio(1);
#pragma unroll
        for (int j = 0; j < 4; ++j) {
          f32x4 z = {};
          z    = MFMA16(ka[j][0], qb[o][s2][0], z);
          t[j] = MFMA16(ka[j][1], qb[o][s2][1], z);
        }
        __builtin_amdgcn_s_setprio(0);
        if (idx > 0) {
          const u16* rP = Ps + w*2048 + ((idx - 1) & 1)*1024;
          paP0 = *(const bf16x8*)&rP[swz(l16, quad, 0)];
          paP1 = *(const bf16x8*)&rP[swz(l16, quad + 4, 0)];
        }
#pragma unroll
        for (int j = 0; j < 4; ++j) {
          u16x4 pk;
#pragma unroll
          for (int reg = 0; reg < 4; ++reg)
            pk[reg] = f2b_trunc(__builtin_amdgcn_exp2f(t[j][reg]));
          *(u16x4*)&wP[swz(l16, j*2 + (quad >> 1), (quad & 1)*4)] = pk;
        }
        if (idx > 0) {
          const int po = (idx - 1) >> 1, ps2 = (idx - 1) & 1;
          __builtin_amdgcn_s_setprio(1);
#pragma unroll
          for (int j = 0; j < 4; ++j) {
            oacc[po][ps2][j] = MFMA16(paP0, vb[j][0], oacc[po][ps2][j]);
            oacc[po][ps2][j] = MFMA16(paP1, vb[j][1], oacc[po][ps2][j]);
          }
          lacc[po][ps2] = MFMA16(paP0, ONES, lacc[po][ps2]);
          lacc[po][ps2] = MFMA16(paP1, ONES, lacc[po][ps2]);
          __builtin_amdgcn_s_setprio(0);
        }
      }
      {
        const u16* rP = Ps + w*2048 + 1024;
        bf16x8 pa0 = *(const bf16x8*)&rP[swz(l16, quad, 0)];
        bf16x8 pa1 = *(const bf16x8*)&rP[swz(l16, quad + 4, 0)];
        __builtin_amdgcn_s_setprio(1);
#pragma unroll
        for (int j = 0; j < 4; ++j) {
          oacc[1][1][j] = MFMA16(pa0, vb[j][0], oacc[1][1][j]);
          oacc[1][1][j] = MFMA16(pa1, vb[j][1], oacc[1][1][j]);
        }
        lacc[1][1] = MFMA16(pa0, ONES, lacc[1][1]);
        lacc[1][1] = MFMA16(pa1, ONES, lacc[1][1]);
        __builtin_amdgcn_s_setprio(0);
      }
    }

#pragma unroll
    for (int o = 0; o < 2; ++o) {
      int a = p + o*2;
      u16* aop = ao + (size_t)a*(4096*512) + (tb + qt*128)*512 + h*64;
#pragma unroll
      for (int s2 = 0; s2 < 2; ++s2) {
#pragma unroll
        for (int reg = 0; reg < 4; ++reg) {
          float linv = 1.f / lacc[o][s2][reg];
          int row = w*32 + s2*16 + quad*4 + reg;
#pragma unroll
          for (int j = 0; j < 4; ++j)
            aop[(size_t)row*512 + j*16 + l16] = f2b(oacc[o][s2][j][reg] * linv);
        }
      }
    }
  } else {
    // ================= ortho path =================
    u16* QnT  = lds;             // [4096]
    u16* QtnT = lds + 4096;      // [4096]

    const int i = blockIdx.x - 512;
    const int bh = i & 31, which = (i >> 5) & 1, tg = i >> 6;  // tg 0..7
    const u16* src = which ? qkv2 : qkv1;
    const int b = bh >> 3, h = bh & 7;
    const size_t tb = (size_t)b * 1024;

    f32x4 gq[4] = {}, gqt[4] = {};
    float diag = 0.f;

    for (int tt = 0; tt < 2; ++tt) {
      int t = tg*2 + tt;
      __syncthreads();
      if (tid < 128) {
        int tok = tid & 63, mat = tid >> 6;
        const u16* pp = src + (tb + t*64 + tok)*2048 + (mat ? 1536 : 0) + h*64;
        u16x8 rowv[8];
#pragma unroll
        for (int ii = 0; ii < 8; ++ii) rowv[ii] = *(const u16x8*)(pp + ii*8);
        float ss = 0.f;
#pragma unroll
        for (int ii = 0; ii < 8; ++ii)
#pragma unroll
          for (int jj = 0; jj < 8; ++jj) { float f = b2f(rowv[ii][jj]); ss += f*f; }
        float inv = 1.f / fmaxf(sqrtf(ss), 1e-12f);
        u16* dst = mat ? QtnT : QnT;
#pragma unroll
        for (int ii = 0; ii < 8; ++ii)
#pragma unroll
          for (int jj = 0; jj < 8; ++jj)
            dst[swz(ii*8 + jj, tok >> 3, tok & 7)] = f2b(b2f(rowv[ii][jj]) * inv);
        if (mat == 0) {
          const u16* p2 = src + (tb + t*64 + tok)*2048 + 1536 + h*64;
          float ss2 = 0.f, dot = 0.f;
#pragma unroll
          for (int ii = 0; ii < 8; ++ii) {
            u16x8 r2 = *(const u16x8*)(p2 + ii*8);
#pragma unroll
            for (int jj = 0; jj < 8; ++jj) {
              float fq = b2f(rowv[ii][jj]), ft = b2f(r2[jj]);
              ss2 += ft*ft; dot += fq*ft;
            }
          }
          float inv2 = 1.f / fmaxf(sqrtf(ss2), 1e-12f);
          float dn = dot * inv * inv2;
          diag += dn * dn;
        }
      }
      __syncthreads();
      bf16x8 a0 = *(const bf16x8*)&QnT [swz(w*16 + l16, quad, 0)];
      bf16x8 a1 = *(const bf16x8*)&QnT [swz(w*16 + l16, quad + 4, 0)];
      bf16x8 t0 = *(const bf16x8*)&QtnT[swz(w*16 + l16, quad, 0)];
      bf16x8 t1 = *(const bf16x8*)&QtnT[swz(w*16 + l16, quad + 4, 0)];
#pragma unroll
      for (int j = 0; j < 4; ++j) {
        bf16x8 b0 = *(const bf16x8*)&QnT [swz(j*16 + l16, quad, 0)];
        bf16x8 b1 = *(const bf16x8*)&QnT [swz(j*16 + l16, quad + 4, 0)];
        gq[j]  = MFMA16(a0, b0, gq[j]);
        gq[j]  = MFMA16(a1, b1, gq[j]);
        bf16x8 c0 = *(const bf16x8*)&QtnT[swz(j*16 + l16, quad, 0)];
        bf16x8 c1 = *(const bf16x8*)&QtnT[swz(j*16 + l16, quad + 4, 0)];
        gqt[j] = MFMA16(t0, c0, gqt[j]);
        gqt[j] = MFMA16(t1, c1, gqt[j]);
      }
    }
    float* Gq = Gbuf + (size_t)((which*32 + bh)*8 + tg) * 8192;
    float* Gt = Gq + 4096;
#pragma unroll
    for (int j = 0; j < 4; ++j)
#pragma unroll
      for (int reg = 0; reg < 4; ++reg) {
        int row = w*16 + quad*4 + reg, col = j*16 + l16;
        Gq[row*64 + col] = gq[j][reg];
        Gt[row*64 + col] = gqt[j][reg];
      }
    if (tid < 64) {
#pragma unroll
      for (int off = 32; off > 0; off >>= 1) diag += __shfl_xor(diag, off);
      if (tid == 0) atomicAdd(&outs[which], -diag * (1.f/4194304.f));
    }
  }
}

// ---------------- lc reduction (pairwise cosine distance of xc,yc) --------------
__global__ __launch_bounds__(256, 2) void red_k(
    const float* __restrict__ dout, float* __restrict__ outs)
{
  const int tid = threadIdx.x;
  const int w = tid >> 6, lane = tid & 63;
  const int wid = blockIdx.x * 4 + w;
  float acc = 0.f;
  for (int rr = 0; rr < 16; ++rr) {
    int row = wid*16 + rr;
    const float4* xr = (const float4*)(dout + (size_t)row*512 + lane*8);
    const float4* yr = (const float4*)(dout + 2097152 + (size_t)row*512 + lane*8);
    float4 x0 = xr[0], x1 = xr[1], y0 = yr[0], y1 = yr[1];
    float dxy = x0.x*y0.x + x0.y*y0.y + x0.z*y0.z + x0.w*y0.w
              + x1.x*y1.x + x1.y*y1.y + x1.z*y1.z + x1.w*y1.w;
    float sx  = x0.x*x0.x + x0.y*x0.y + x0.z*x0.z + x0.w*x0.w
              + x1.x*x1.x + x1.y*x1.y + x1.z*x1.z + x1.w*x1.w;
    float sy  = y0.x*y0.x + y0.y*y0.y + y0.z*y0.z + y0.w*y0.w
              + y1.x*y1.x + y1.y*y1.y + y1.z*y1.z + y1.w*y1.w;
#pragma unroll
    for (int off = 32; off > 0; off >>= 1) {
      dxy += __shfl_xor(dxy, off);
      sx  += __shfl_xor(sx,  off);
      sy  += __shfl_xor(sy,  off);
    }
    if (lane == 0) {
      float cosv = dxy / (fmaxf(sqrtf(sx), 1e-12f) * fmaxf(sqrtf(sy), 1e-12f));
      acc += 1.f - cosv;
    }
  }
  if (lane == 0) atomicAdd(&outs[2], acc * (1.f/4096.f));
}

extern "C" void kernel_launch(void* const* d_in, const int* in_sizes, int n_in,
                              void* d_out, int out_size, void* d_ws, size_t ws_size,
                              hipStream_t stream)
{
  (void)in_sizes; (void)n_in; (void)out_size; (void)ws_size;
  const float* x     = (const float*)d_in[0];
  const float* y     = (const float*)d_in[1];
  const float* Wqkv1 = (const float*)d_in[2];
  const float* Wqkv2 = (const float*)d_in[3];
  const float* W1 = (const float*)d_in[4];
  const float* b1 = (const float*)d_in[5];
  const float* W2 = (const float*)d_in[6];
  const float* b2 = (const float*)d_in[7];
  const float* W3 = (const float*)d_in[8];
  const float* b3 = (const float*)d_in[9];
  const float* W4 = (const float*)d_in[10];
  const float* b4 = (const float*)d_in[11];

  u16* ws   = (u16*)d_ws;
  u16* xb   = ws;                                  // x,y: 2 x 2097152
  u16* Wq1b = ws + (size_t)4194304;                // 2 x 1048576
  u16* W1b  = ws + (size_t)6291456;                // 4 x 262144
  u16* qkv1 = ws + (size_t)7340032;                // 2 x 8388608
  u16* qkv2 = qkv1 + (size_t)8388608;
  u16* aob  = qkv2 + (size_t)8388608;              // 4 x 2097152
  float* Gbuf = (float*)(aob + (size_t)8388608);   // 64 groups x 8 tg x 8192 f32 = 16 MB
  // V^T buffers live in d_out (consumed by attn before final GEMM overwrites)
  u16* vT1 = (u16*)d_out;                          // 512 x 4096 each
  u16* vT2 = vT1 + (size_t)2097152;

  float* outb = (float*)d_out;
  float* outs = outb + 8388608;                    // 3 loss scalars

  cast_all_k<<<dim3(7168), dim3(256), 0, stream>>>(
      x, y, Wqkv1, Wqkv2, W1, W2, W3, W4, xb, outs);

  qkv_mega_k<<<dim3(1024), dim3(256), 0, stream>>>(xb, Wq1b, qkv1, vT1);

  attn_ortho_k<<<dim3(1024), 256, 0, stream>>>(qkv1, qkv2, vT1, vT2, aob, Gbuf, outs);

  gemm_fin_k<<<dim3(576), 256, 0, stream>>>(
      aob, 2097152, W1b, 262144, b1, b2, b3, b4, outb, 2097152, Gbuf, outs);

  red_k<<<dim3(64), 256, 0, stream>>>(outb, outs);
}

// Round 9
// 205.264 us; speedup vs baseline: 1.0418x; 1.0418x over previous
//
#include <hip/hip_runtime.h>

typedef unsigned short u16;
typedef __attribute__((ext_vector_type(4))) unsigned short u16x4;
typedef __attribute__((ext_vector_type(8))) unsigned short u16x8;
typedef __attribute__((ext_vector_type(4))) float          f32x4;
typedef __attribute__((ext_vector_type(8))) __bf16         bf16x8;

#define MFMA16(a,b,c) __builtin_amdgcn_mfma_f32_16x16x32_bf16((a),(b),(c),0,0,0)
#define SCALE 0.125f
// SCALE * log2(e): exp(s*SCALE) == exp2(s * SCALE_LOG2E). Folded into q/qt weights.
#define SCALE_LOG2E 0.18033688011112042f

__device__ __forceinline__ u16 f2b(float f){
  unsigned u = __builtin_bit_cast(unsigned, f);
  u = (u + 0x7fffu + ((u >> 16) & 1u)) >> 16;
  return (u16)u;
}
__device__ __forceinline__ u16 f2b_trunc(float f){
  return (u16)(__builtin_bit_cast(unsigned, f) >> 16);
}
__device__ __forceinline__ float b2f(u16 v){
  unsigned u = ((unsigned)v) << 16;
  return __builtin_bit_cast(float, u);
}
__device__ __forceinline__ void async16(const u16* g, u16* l){
  __builtin_amdgcn_global_load_lds(
      (const __attribute__((address_space(1))) unsigned*)g,
      (__attribute__((address_space(3))) unsigned*)l, 16, 0, 0);
}
// XOR-swizzled LDS addressing: rows of 64 u16 = 8 chunks of 8.
__device__ __forceinline__ int swz(int row, int chunk, int off){
  return row*64 + (((chunk ^ row ^ (row >> 3)) & 7) << 3) + off;
}

// ---------------- fused cast f32 -> bf16 over all 8 inputs ----------------
// q rows (0..511) and qt rows (1536..2047) of Wqkv are pre-scaled by
// SCALE*log2e so attention scores land directly in the exp2 domain.
// Block 0 also zeroes the 3 output-loss slots (stream order makes this safe:
// every atomicAdd into outs happens in a later launch).
__global__ void cast_all_k(const float* __restrict__ x, const float* __restrict__ y,
                           const float* __restrict__ wq1, const float* __restrict__ wq2,
                           const float* __restrict__ w1, const float* __restrict__ w2,
                           const float* __restrict__ w3, const float* __restrict__ w4,
                           u16* __restrict__ dst, float* __restrict__ outs){
  if (blockIdx.x == 0 && threadIdx.x < 3) outs[threadIdx.x] = 0.f;
  int i = blockIdx.x * 256 + threadIdx.x;            // float4 index, 1,835,008 total
  const float* s; int base; float sc = 1.f;
  if      (i < 524288)  { s = x;   base = 0;       }
  else if (i < 1048576) { s = y;   base = 524288;  }
  else if (i < 1310720) { s = wq1; base = 1048576;
    int iw = i - base; if (iw < 65536 || iw >= 196608) sc = SCALE_LOG2E; }
  else if (i < 1572864) { s = wq2; base = 1310720;
    int iw = i - base; if (iw < 65536 || iw >= 196608) sc = SCALE_LOG2E; }
  else if (i < 1638400) { s = w1;  base = 1572864; }
  else if (i < 1703936) { s = w2;  base = 1638400; }
  else if (i < 1769472) { s = w3;  base = 1703936; }
  else                  { s = w4;  base = 1769472; }
  float4 v = ((const float4*)s)[i - base];
  u16x4 o; o[0]=f2b(v.x*sc); o[1]=f2b(v.y*sc); o[2]=f2b(v.z*sc); o[3]=f2b(v.w*sc);
  ((u16x4*)dst)[i] = o;
}

// ---------------- mega QKV GEMM: all q/k/qt/vT tiles in one launch ----------------
// All sub-GEMMs share K=512 and row-stride-512 A,B. bf16 out. (round-3 proven form)
__global__ __launch_bounds__(256, 2) void qkv_mega_k(
    const u16* __restrict__ xb, const u16* __restrict__ Wq,
    u16* __restrict__ qkv, u16* __restrict__ vT)
{
  const int i = blockIdx.x;
  const u16 *A, *B; u16* C; int ldc, m0, n0;
  if (i < 512) {                 // q,k: M=4096,N=1024
    int z = i >> 8, t = i & 255;
    m0 = (t & 31)*128; n0 = (t >> 5)*128;
    A = xb + (size_t)z*2097152; B = Wq + (size_t)z*1048576;
    C = qkv + (size_t)z*8388608; ldc = 2048;
  } else if (i < 768) {          // qt: M=4096,N=512 -> cols 1536..2047
    int z = (i-512) >> 7, t = (i-512) & 127;
    m0 = (t & 31)*128; n0 = (t >> 5)*128;
    A = xb + (size_t)z*2097152; B = Wq + (size_t)z*1048576 + (size_t)1536*512;
    C = qkv + (size_t)z*8388608 + 1536; ldc = 2048;
  } else {                       // vT = Wv @ x^T: M=512,N=4096
    int z = (i-768) >> 7, t = (i-768) & 127;
    m0 = (t & 3)*128; n0 = (t >> 2)*128;
    A = Wq + (size_t)z*1048576 + (size_t)1024*512; B = xb + (size_t)z*2097152;
    C = vT + (size_t)z*2097152; ldc = 4096;
  }

  __shared__ u16 As[128*32];
  __shared__ u16 Bs[128*32];
  const int tid  = threadIdx.x;
  const int w    = tid >> 6, lane = tid & 63;
  const int quad = lane >> 4, l16 = lane & 15;
  const int wr   = w >> 1, wc = w & 1;

  f32x4 acc[4][4] = {};
  const int rowa = lane >> 2;
  const int ko   = (lane & 3) * 8;

  for (int k0 = 0; k0 < 512; k0 += 32) {
    __syncthreads();
#pragma unroll
    for (int r = 0; r < 2; ++r) {
      int rb = (r*4 + w) * 16;
      async16(A + (size_t)(m0 + rb + rowa)*512 + k0 + ko, As + (r*4 + w)*512);
      async16(B + (size_t)(n0 + rb + rowa)*512 + k0 + ko, Bs + (r*4 + w)*512);
    }
    __syncthreads();
    bf16x8 af[4], bfr[4];
#pragma unroll
    for (int ii = 0; ii < 4; ++ii)
      af[ii] = *(const bf16x8*)&As[(wr*64 + ii*16 + l16)*32 + quad*8];
#pragma unroll
    for (int j = 0; j < 4; ++j)
      bfr[j] = *(const bf16x8*)&Bs[(wc*64 + j*16 + l16)*32 + quad*8];
#pragma unroll
    for (int ii = 0; ii < 4; ++ii)
#pragma unroll
      for (int j = 0; j < 4; ++j)
        acc[ii][j] = MFMA16(af[ii], bfr[j], acc[ii][j]);
  }
#pragma unroll
  for (int j = 0; j < 4; ++j) {
    int col = n0 + wc*64 + j*16 + l16;
#pragma unroll
    for (int ii = 0; ii < 4; ++ii)
#pragma unroll
      for (int reg = 0; reg < 4; ++reg) {
        int row = m0 + wr*64 + ii*16 + quad*4 + reg;
        C[(size_t)row*ldc + col] = f2b(acc[ii][j][reg]);
      }
  }
}

// ------- final-linear GEMM (blocks 0..511) + orthoB reduction (512..575) ----
// GEMM: C[M,N] = A @ B^T + bias, f32 out, z = bid>>7. (round-3 proven body)
// orthoB blocks are independent of the GEMM (read Gbuf from attn_ortho) and
// run in the GEMM's occupancy shadow; they atomicAdd pre-scaled loss to outs.
__global__ __launch_bounds__(256, 2) void gemm_fin_k(
    const u16* __restrict__ A0, size_t aStr, const u16* __restrict__ B0, size_t bStr,
    const float* __restrict__ bias0, const float* __restrict__ bias1,
    const float* __restrict__ bias2, const float* __restrict__ bias3,
    float* __restrict__ C0, size_t cStr,
    const float* __restrict__ Gbuf, float* __restrict__ outs)
{
  const int tid  = threadIdx.x;
  const int bid  = blockIdx.x;
  if (bid >= 512) {
    // ---- orthoB: sum 4 tp-partials, Hadamard, reduce, pre-scaled add ----
    const int i = bid - 512;
    const int bh = i & 31, which = i >> 5;
    const float* base = Gbuf + (size_t)((which*32 + bh)*4) * 8192;
    float acc = 0.f;
    for (int idx = tid*4; idx < 4096; idx += 1024) {
      float4 gq = {0.f,0.f,0.f,0.f}, gt = {0.f,0.f,0.f,0.f};
#pragma unroll
      for (int t = 0; t < 4; ++t) {
        float4 a = *(const float4*)(base + (size_t)t*8192 + idx);
        float4 c = *(const float4*)(base + (size_t)t*8192 + 4096 + idx);
        gq.x += a.x; gq.y += a.y; gq.z += a.z; gq.w += a.w;
        gt.x += c.x; gt.y += c.y; gt.z += c.z; gt.w += c.w;
      }
      acc += gq.x*gt.x + gq.y*gt.y + gq.z*gt.z + gq.w*gt.w;
    }
    __shared__ float redsh[256];
    redsh[tid] = acc; __syncthreads();
    for (int s2 = 128; s2 > 0; s2 >>= 1) {
      if (tid < s2) redsh[tid] += redsh[tid + s2];
      __syncthreads();
    }
    if (tid == 0) atomicAdd(&outs[which], redsh[0] * (1.f/4194304.f));
    return;
  }

  const int z = bid >> 7, t7 = bid & 127;
  const int m0 = (t7 >> 2) * 128, n0 = (t7 & 3) * 128;
  const u16* A = A0 + (size_t)z * aStr;
  const u16* Bm = B0 + (size_t)z * bStr;
  float* Cb = C0 + (size_t)z * cStr;
  const float* bias = (z==0) ? bias0 : (z==1) ? bias1 : (z==2) ? bias2 : bias3;

  __shared__ u16 As[128*32];
  __shared__ u16 Bs[128*32];
  const int w    = tid >> 6, lane = tid & 63;
  const int quad = lane >> 4, l16 = lane & 15;
  const int wr   = w >> 1, wc = w & 1;

  f32x4 acc[4][4] = {};
  const int rowa = lane >> 2;
  const int ko   = (lane & 3) * 8;

  for (int k0 = 0; k0 < 512; k0 += 32) {
    __syncthreads();
#pragma unroll
    for (int r = 0; r < 2; ++r) {
      int rb = (r*4 + w) * 16;
      async16(A  + (size_t)(m0 + rb + rowa)*512 + k0 + ko, As + (r*4 + w)*512);
      async16(Bm + (size_t)(n0 + rb + rowa)*512 + k0 + ko, Bs + (r*4 + w)*512);
    }
    __syncthreads();
    bf16x8 af[4], bfr[4];
#pragma unroll
    for (int ii = 0; ii < 4; ++ii)
      af[ii] = *(const bf16x8*)&As[(wr*64 + ii*16 + l16)*32 + quad*8];
#pragma unroll
    for (int j = 0; j < 4; ++j)
      bfr[j] = *(const bf16x8*)&Bs[(wc*64 + j*16 + l16)*32 + quad*8];
#pragma unroll
    for (int ii = 0; ii < 4; ++ii)
#pragma unroll
      for (int j = 0; j < 4; ++j)
        acc[ii][j] = MFMA16(af[ii], bfr[j], acc[ii][j]);
  }
#pragma unroll
  for (int j = 0; j < 4; ++j) {
    int col = n0 + wc*64 + j*16 + l16;
    float bv = bias[col];
#pragma unroll
    for (int ii = 0; ii < 4; ++ii)
#pragma unroll
      for (int reg = 0; reg < 4; ++reg) {
        int row = m0 + wr*64 + ii*16 + quad*4 + reg;
        Cb[(size_t)row*512 + col] = acc[ii][j][reg] + bv;
      }
  }
}

// ---------------- merged attention + ortho: grid 768 = full residency ----------
// Blocks 0..511: flash attention (round-5 proven body, XCD swizzle preserved).
// Blocks 512..767: ortho Gram partials, 4 token-tiles each (was 2 over 512
// blocks). 48 KB LDS -> 3 blocks/CU -> all 768 blocks resident in ONE wave:
// no tail pass, and each CU hosts ~2 attn + 1 ortho so the ortho VALU/LDS
// work fills attn's MFMA-stall cycles for the whole kernel duration.
__global__ __launch_bounds__(256, 2) void attn_ortho_k(
    const u16* __restrict__ qkv1, const u16* __restrict__ qkv2,
    const u16* __restrict__ vT1, const u16* __restrict__ vT2,
    u16* __restrict__ ao, float* __restrict__ Gbuf, float* __restrict__ outs)
{
  __shared__ u16 lds[24576];     // 48 KB union
  const int tid = threadIdx.x, w = tid >> 6, lane = tid & 63;
  const int quad = lane >> 4, l16 = lane & 15;

  if (blockIdx.x < 512) {
    // ================= attention path =================
    u16* Ks = lds;               // [2][4096]
    u16* Vt = lds + 8192;        // [2][4096]
    u16* Ps = lds + 16384;       // [4][2][1024]

    const int lin = blockIdx.x;
    const int xcd = lin & 7, slot = lin >> 3;        // slot 0..63
    const int g   = xcd + 8*(slot >> 3);             // group 0..63, g%8 == xcd
    const int qt  = slot & 7;                        // 8 q-tiles of 128 rows
    const int bh  = g >> 1, p = g & 1;
    const int b = bh >> 3, h = bh & 7;
    const u16* kvsrc = p ? qkv2 : qkv1;
    const u16* vsrc  = p ? vT2 : vT1;
    const u16* qsrcA = p ? qkv1 : qkv2;  const int qoffA = h*64;           // out a=p
    const u16* qsrcB = p ? qkv2 : qkv1;  const int qoffB = 1536 + h*64;    // out a=p+2
    const int koff = 512 + h*64;
    const size_t tb = (size_t)b * 1024;

    const int srow = tid >> 3, sch = tid & 7;

    u16x8 onesu;
#pragma unroll
    for (int ii = 0; ii < 8; ++ii) onesu[ii] = 0x3f80;
    const bf16x8 ONES = __builtin_bit_cast(bf16x8, onesu);

    bf16x8 qb[2][2][2];
#pragma unroll
    for (int s2 = 0; s2 < 2; ++s2) {
      size_t row = tb + qt*128 + w*32 + s2*16 + l16;
      const u16* qrA = qsrcA + row*2048 + qoffA;
      const u16* qrB = qsrcB + row*2048 + qoffB;
      qb[0][s2][0] = *(const bf16x8*)(qrA + quad*8);
      qb[0][s2][1] = *(const bf16x8*)(qrA + 32 + quad*8);
      qb[1][s2][0] = *(const bf16x8*)(qrB + quad*8);
      qb[1][s2][1] = *(const bf16x8*)(qrB + 32 + quad*8);
    }

    f32x4 oacc[2][2][4] = {};
    f32x4 lacc[2][2] = {};

    u16x8 kreg[2], vreg[2];
    auto loadTile = [&](int t){
#pragma unroll
      for (int r = 0; r < 2; ++r) {
        kreg[r] = *(const u16x8*)(kvsrc + (tb + t*64 + r*32 + srow)*2048 + koff + sch*8);
        vreg[r] = *(const u16x8*)(vsrc + (size_t)(h*64 + r*32 + srow)*4096 + tb + t*64 + sch*8);
      }
    };
    auto storeTile = [&](int buf){
#pragma unroll
      for (int r = 0; r < 2; ++r) {
        *(u16x8*)&Ks[buf*4096 + swz(r*32 + srow, sch, 0)] = kreg[r];
        *(u16x8*)&Vt[buf*4096 + swz(r*32 + srow, sch, 0)] = vreg[r];
      }
    };

    loadTile(0);
    storeTile(0);
    loadTile(1);

    for (int kt = 0; kt < 16; ++kt) {
      const int cur = kt & 1;
      __syncthreads();
      if (kt < 15) storeTile(cur ^ 1);
      if (kt < 14) loadTile(kt + 2);

      bf16x8 ka[4][2], vb[4][2];
#pragma unroll
      for (int j = 0; j < 4; ++j) {
        ka[j][0] = *(const bf16x8*)&Ks[cur*4096 + swz(j*16 + l16, quad, 0)];
        ka[j][1] = *(const bf16x8*)&Ks[cur*4096 + swz(j*16 + l16, quad + 4, 0)];
        vb[j][0] = *(const bf16x8*)&Vt[cur*4096 + swz(j*16 + l16, quad, 0)];
        vb[j][1] = *(const bf16x8*)&Vt[cur*4096 + swz(j*16 + l16, quad + 4, 0)];
      }

      bf16x8 paP0, paP1;
#pragma unroll
      for (int idx = 0; idx < 4; ++idx) {
        const int o = idx >> 1, s2 = idx & 1;
        u16* wP = Ps + w*2048 + (idx & 1)*1024;
        f32x4 t[4];
        __builtin_amdgcn_s_setprio(1);
#pragma unroll
        for (int j = 0; j < 4; ++j) {
          f32x4 z = {};
          z    = MFMA16(ka[j][0], qb[o][s2][0], z);
          t[j] = MFMA16(ka[j][1], qb[o][s2][1], z);
        }
        __builtin_amdgcn_s_setprio(0);
        if (idx > 0) {
          const u16* rP = Ps + w*2048 + ((idx - 1) & 1)*1024;
          paP0 = *(const bf16x8*)&rP[swz(l16, quad, 0)];
          paP1 = *(const bf16x8*)&rP[swz(l16, quad + 4, 0)];
        }
#pragma unroll
        for (int j = 0; j < 4; ++j) {
          u16x4 pk;
#pragma unroll
          for (int reg = 0; reg < 4; ++reg)
            pk[reg] = f2b_trunc(__builtin_amdgcn_exp2f(t[j][reg]));
          *(u16x4*)&wP[swz(l16, j*2 + (quad >> 1), (quad & 1)*4)] = pk;
        }
        if (idx > 0) {
          const int po = (idx - 1) >> 1, ps2 = (idx - 1) & 1;
          __builtin_amdgcn_s_setprio(1);
#pragma unroll
          for (int j = 0; j < 4; ++j) {
            oacc[po][ps2][j] = MFMA16(paP0, vb[j][0], oacc[po][ps2][j]);
            oacc[po][ps2][j] = MFMA16(paP1, vb[j][1], oacc[po][ps2][j]);
          }
          lacc[po][ps2] = MFMA16(paP0, ONES, lacc[po][ps2]);
          lacc[po][ps2] = MFMA16(paP1, ONES, lacc[po][ps2]);
          __builtin_amdgcn_s_setprio(0);
        }
      }
      {
        const u16* rP = Ps + w*2048 + 1024;
        bf16x8 pa0 = *(const bf16x8*)&rP[swz(l16, quad, 0)];
        bf16x8 pa1 = *(const bf16x8*)&rP[swz(l16, quad + 4, 0)];
        __builtin_amdgcn_s_setprio(1);
#pragma unroll
        for (int j = 0; j < 4; ++j) {
          oacc[1][1][j] = MFMA16(pa0, vb[j][0], oacc[1][1][j]);
          oacc[1][1][j] = MFMA16(pa1, vb[j][1], oacc[1][1][j]);
        }
        lacc[1][1] = MFMA16(pa0, ONES, lacc[1][1]);
        lacc[1][1] = MFMA16(pa1, ONES, lacc[1][1]);
        __builtin_amdgcn_s_setprio(0);
      }
    }

#pragma unroll
    for (int o = 0; o < 2; ++o) {
      int a = p + o*2;
      u16* aop = ao + (size_t)a*(4096*512) + (tb + qt*128)*512 + h*64;
#pragma unroll
      for (int s2 = 0; s2 < 2; ++s2) {
#pragma unroll
        for (int reg = 0; reg < 4; ++reg) {
          float linv = 1.f / lacc[o][s2][reg];
          int row = w*32 + s2*16 + quad*4 + reg;
#pragma unroll
          for (int j = 0; j < 4; ++j)
            aop[(size_t)row*512 + j*16 + l16] = f2b(oacc[o][s2][j][reg] * linv);
        }
      }
    }
  } else {
    // ================= ortho path: 4 token-tiles per block =================
    u16* QnT  = lds;             // [4096]
    u16* QtnT = lds + 4096;      // [4096]

    const int i = blockIdx.x - 512;                  // 0..255
    const int bh = i & 31, which = (i >> 5) & 1, tp = i >> 6;  // tp 0..3
    const u16* src = which ? qkv2 : qkv1;
    const int b = bh >> 3, h = bh & 7;
    const size_t tb = (size_t)b * 1024;

    f32x4 gq[4] = {}, gqt[4] = {};
    float diag = 0.f;

    for (int tt = 0; tt < 4; ++tt) {
      int t = tp*4 + tt;
      __syncthreads();
      if (tid < 128) {
        int tok = tid & 63, mat = tid >> 6;
        const u16* pp = src + (tb + t*64 + tok)*2048 + (mat ? 1536 : 0) + h*64;
        u16x8 rowv[8];
#pragma unroll
        for (int ii = 0; ii < 8; ++ii) rowv[ii] = *(const u16x8*)(pp + ii*8);
        float ss = 0.f;
#pragma unroll
        for (int ii = 0; ii < 8; ++ii)
#pragma unroll
          for (int jj = 0; jj < 8; ++jj) { float f = b2f(rowv[ii][jj]); ss += f*f; }
        float inv = 1.f / fmaxf(sqrtf(ss), 1e-12f);
        u16* dst = mat ? QtnT : QnT;
#pragma unroll
        for (int ii = 0; ii < 8; ++ii)
#pragma unroll
          for (int jj = 0; jj < 8; ++jj)
            dst[swz(ii*8 + jj, tok >> 3, tok & 7)] = f2b(b2f(rowv[ii][jj]) * inv);
        if (mat == 0) {
          const u16* p2 = src + (tb + t*64 + tok)*2048 + 1536 + h*64;
          float ss2 = 0.f, dot = 0.f;
#pragma unroll
          for (int ii = 0; ii < 8; ++ii) {
            u16x8 r2 = *(const u16x8*)(p2 + ii*8);
#pragma unroll
            for (int jj = 0; jj < 8; ++jj) {
              float fq = b2f(rowv[ii][jj]), ft = b2f(r2[jj]);
              ss2 += ft*ft; dot += fq*ft;
            }
          }
          float inv2 = 1.f / fmaxf(sqrtf(ss2), 1e-12f);
          float dn = dot * inv * inv2;
          diag += dn * dn;
        }
      }
      __syncthreads();
      bf16x8 a0 = *(const bf16x8*)&QnT [swz(w*16 + l16, quad, 0)];
      bf16x8 a1 = *(const bf16x8*)&QnT [swz(w*16 + l16, quad + 4, 0)];
      bf16x8 t0 = *(const bf16x8*)&QtnT[swz(w*16 + l16, quad, 0)];
      bf16x8 t1 = *(const bf16x8*)&QtnT[swz(w*16 + l16, quad + 4, 0)];
#pragma unroll
      for (int j = 0; j < 4; ++j) {
        bf16x8 b0 = *(const bf16x8*)&QnT [swz(j*16 + l16, quad, 0)];
        bf16x8 b1 = *(const bf16x8*)&QnT [swz(j*16 + l16, quad + 4, 0)];
        gq[j]  = MFMA16(a0, b0, gq[j]);
        gq[j]  = MFMA16(a1, b1, gq[j]);
        bf16x8 c0 = *(const bf16x8*)&QtnT[swz(j*16 + l16, quad, 0)];
        bf16x8 c1 = *(const bf16x8*)&QtnT[swz(j*16 + l16, quad + 4, 0)];
        gqt[j] = MFMA16(t0, c0, gqt[j]);
        gqt[j] = MFMA16(t1, c1, gqt[j]);
      }
    }
    float* Gq = Gbuf + (size_t)((which*32 + bh)*4 + tp) * 8192;
    float* Gt = Gq + 4096;
#pragma unroll
    for (int j = 0; j < 4; ++j)
#pragma unroll
      for (int reg = 0; reg < 4; ++reg) {
        int row = w*16 + quad*4 + reg, col = j*16 + l16;
        Gq[row*64 + col] = gq[j][reg];
        Gt[row*64 + col] = gqt[j][reg];
      }
    if (tid < 64) {
#pragma unroll
      for (int off = 32; off > 0; off >>= 1) diag += __shfl_xor(diag, off);
      if (tid == 0) atomicAdd(&outs[which], -diag * (1.f/4194304.f));
    }
  }
}

// ---------------- lc reduction (pairwise cosine distance of xc,yc) --------------
__global__ __launch_bounds__(256, 2) void red_k(
    const float* __restrict__ dout, float* __restrict__ outs)
{
  const int tid = threadIdx.x;
  const int w = tid >> 6, lane = tid & 63;
  const int wid = blockIdx.x * 4 + w;
  float acc = 0.f;
  for (int rr = 0; rr < 16; ++rr) {
    int row = wid*16 + rr;
    const float4* xr = (const float4*)(dout + (size_t)row*512 + lane*8);
    const float4* yr = (const float4*)(dout + 2097152 + (size_t)row*512 + lane*8);
    float4 x0 = xr[0], x1 = xr[1], y0 = yr[0], y1 = yr[1];
    float dxy = x0.x*y0.x + x0.y*y0.y + x0.z*y0.z + x0.w*y0.w
              + x1.x*y1.x + x1.y*y1.y + x1.z*y1.z + x1.w*y1.w;
    float sx  = x0.x*x0.x + x0.y*x0.y + x0.z*x0.z + x0.w*x0.w
              + x1.x*x1.x + x1.y*x1.y + x1.z*x1.z + x1.w*x1.w;
    float sy  = y0.x*y0.x + y0.y*y0.y + y0.z*y0.z + y0.w*y0.w
              + y1.x*y1.x + y1.y*y1.y + y1.z*y1.z + y1.w*y1.w;
#pragma unroll
    for (int off = 32; off > 0; off >>= 1) {
      dxy += __shfl_xor(dxy, off);
      sx  += __shfl_xor(sx,  off);
      sy  += __shfl_xor(sy,  off);
    }
    if (lane == 0) {
      float cosv = dxy / (fmaxf(sqrtf(sx), 1e-12f) * fmaxf(sqrtf(sy), 1e-12f));
      acc += 1.f - cosv;
    }
  }
  if (lane == 0) atomicAdd(&outs[2], acc * (1.f/4096.f));
}

extern "C" void kernel_launch(void* const* d_in, const int* in_sizes, int n_in,
                              void* d_out, int out_size, void* d_ws, size_t ws_size,
                              hipStream_t stream)
{
  (void)in_sizes; (void)n_in; (void)out_size; (void)ws_size;
  const float* x     = (const float*)d_in[0];
  const float* y     = (const float*)d_in[1];
  const float* Wqkv1 = (const float*)d_in[2];
  const float* Wqkv2 = (const float*)d_in[3];
  const float* W1 = (const float*)d_in[4];
  const float* b1 = (const float*)d_in[5];
  const float* W2 = (const float*)d_in[6];
  const float* b2 = (const float*)d_in[7];
  const float* W3 = (const float*)d_in[8];
  const float* b3 = (const float*)d_in[9];
  const float* W4 = (const float*)d_in[10];
  const float* b4 = (const float*)d_in[11];

  u16* ws   = (u16*)d_ws;
  u16* xb   = ws;                                  // x,y: 2 x 2097152
  u16* Wq1b = ws + (size_t)4194304;                // 2 x 1048576
  u16* W1b  = ws + (size_t)6291456;                // 4 x 262144
  u16* qkv1 = ws + (size_t)7340032;                // 2 x 8388608
  u16* qkv2 = qkv1 + (size_t)8388608;
  u16* aob  = qkv2 + (size_t)8388608;              // 4 x 2097152
  float* Gbuf = (float*)(aob + (size_t)8388608);   // 64 groups x 4 tp x 8192 f32 = 8 MB
  // V^T buffers live in d_out (consumed by attn before final GEMM overwrites)
  u16* vT1 = (u16*)d_out;                          // 512 x 4096 each
  u16* vT2 = vT1 + (size_t)2097152;

  float* outb = (float*)d_out;
  float* outs = outb + 8388608;                    // 3 loss scalars

  cast_all_k<<<dim3(7168), dim3(256), 0, stream>>>(
      x, y, Wqkv1, Wqkv2, W1, W2, W3, W4, xb, outs);

  qkv_mega_k<<<dim3(1024), dim3(256), 0, stream>>>(xb, Wq1b, qkv1, vT1);

  attn_ortho_k<<<dim3(768), 256, 0, stream>>>(qkv1, qkv2, vT1, vT2, aob, Gbuf, outs);

  gemm_fin_k<<<dim3(576), 256, 0, stream>>>(
      aob, 2097152, W1b, 262144, b1, b2, b3, b4, outb, 2097152, Gbuf, outs);

  red_k<<<dim3(64), 256, 0, stream>>>(outb, outs);
}